// Round 6
// baseline (591.047 us; speedup 1.0000x reference)
//
#include <hip/hip_runtime.h>

#define BATCH   2048
#define NFIELDS 40
#define EMB     64
#define PAIRS   780
#define BM      128
#define NTILES  (BATCH / BM)          // 16
#define NBLOCKS (PAIRS * NTILES)      // 12480
#define FEMB_ELEMS (BATCH * NFIELDS * EMB)   // 5,242,880
#define W_ELEMS    (PAIRS * EMB * EMB)       // 3,194,880

typedef __attribute__((ext_vector_type(8))) short          short8;
typedef __attribute__((ext_vector_type(8))) unsigned short ushort8;
typedef __attribute__((ext_vector_type(4))) float          fvec4;

__device__ __forceinline__ unsigned short f2bf(float f) {
    unsigned int x = __float_as_uint(f);
    return (unsigned short)((x + 0x7fffu + ((x >> 16) & 1u)) >> 16);  // RTNE
}
__device__ __forceinline__ float bf2f(unsigned short h) {
    return __uint_as_float(((unsigned int)h) << 16);
}
struct bfpair { unsigned short h, l; };
__device__ __forceinline__ bfpair split1(float f) {
    bfpair r;
    r.h = f2bf(f);
    r.l = f2bf(f - bf2f(r.h));
    return r;
}

// ---- prep 1: femb fp32 -> Fh/Fl bf16, same [b][f][k] layout ----
__global__ __launch_bounds__(256) void prep_femb(
    const float* __restrict__ femb, unsigned short* __restrict__ Fh,
    unsigned short* __restrict__ Fl)
{
    int tid  = blockIdx.x * 256 + threadIdx.x;
    int base = tid * 8;                       // 8 elements per thread
    fvec4 a = *(const fvec4*)&femb[base];
    fvec4 b = *(const fvec4*)&femb[base + 4];
    ushort8 hi, lo;
    #pragma unroll
    for (int i = 0; i < 4; ++i) {
        bfpair s0 = split1(a[i]);
        hi[i] = s0.h; lo[i] = s0.l;
        bfpair s1 = split1(b[i]);
        hi[i + 4] = s1.h; lo[i + 4] = s1.l;
    }
    *(ushort8*)&Fh[base] = hi;
    *(ushort8*)&Fl[base] = lo;
}

// ---- prep 2: W fp32 [p][k][e] -> Wh/Wl bf16 TRANSPOSED [p][e][k] ----
__global__ __launch_bounds__(256) void prep_w(
    const float* __restrict__ W, unsigned short* __restrict__ Wh,
    unsigned short* __restrict__ Wl)
{
    __shared__ float Ws[EMB * EMB];           // 16 KB, [k][e] linear copy
    int p = blockIdx.x;
    int t = threadIdx.x;
    const float* Wp = W + (size_t)p * (EMB * EMB);
    #pragma unroll
    for (int j = 0; j < 4; ++j)               // 16 floats per thread, coalesced
        *(fvec4*)&Ws[t * 16 + j * 4] = *(const fvec4*)&Wp[t * 16 + j * 4];
    __syncthreads();

    int e  = t & 63;
    int k0 = (t >> 6) * 16;
    #pragma unroll
    for (int j = 0; j < 2; ++j) {
        int k = k0 + j * 8;
        ushort8 hi, lo;
        #pragma unroll
        for (int i = 0; i < 8; ++i) {
            bfpair s = split1(Ws[(k + i) * EMB + e]);   // 2 lanes/bank: free
            hi[i] = s.h; lo[i] = s.l;
        }
        size_t dst = (size_t)p * (EMB * EMB) + e * EMB + k;
        *(ushort8*)&Wh[dst] = hi;
        *(ushort8*)&Wl[dst] = lo;
    }
}

// ---- main: barrier-free register MFMA GEMM ----
// out[b][p][e] = (sum_k femb[b][lp][k] * W[p][k][e]) * femb[b][rp][e]
// D = A*B with A = W^T fragments (row=e), B = L fragments (col=b):
//   lane r=l&15, g=l>>4. A: lane holds Wt[e=n*16+r][k=kk*32+g*8 ..+8]
//                        B: lane holds  L[b=tile+r]  [k=kk*32+g*8 ..+8]
//   D: col = r -> b ; row = g*4+reg -> e  => fvec4 epilogue on e. (m89/m91)
__global__ __launch_bounds__(256, 4) void bilinear_main(
    const unsigned short* __restrict__ Fh, const unsigned short* __restrict__ Fl,
    const unsigned short* __restrict__ Wh, const unsigned short* __restrict__ Wl,
    const float* __restrict__ femb,
    const int* __restrict__ lidx, const int* __restrict__ ridx,
    float* __restrict__ out)
{
    // Bijective XCD swizzle (12480 % 8 == 0): each XCD owns a contiguous
    // p-range -> its Wh/Wl slice (~1.6MB) stays L2-resident.
    int d  = blockIdx.x;
    int w  = (d & 7) * (NBLOCKS / 8) + (d >> 3);
    int p  = w >> 4;
    int b0 = (w & 15) * BM;

    int lp = lidx[p];
    int rp = ridx[p];
    int t  = threadIdx.x;
    int wv = t >> 6;
    int l  = t & 63;
    int r  = l & 15;
    int g  = l >> 4;

    const unsigned short* WhP = Wh + (size_t)p * (EMB * EMB);
    const unsigned short* WlP = Wl + (size_t)p * (EMB * EMB);

    fvec4 acc[2][4] = {};
    #pragma unroll
    for (int kk = 0; kk < 2; ++kk) {
        short8 Ah[4], Al[4], Bh[2], Bl[2];
        #pragma unroll
        for (int n = 0; n < 4; ++n) {
            int off = (n * 16 + r) * EMB + kk * 32 + g * 8;
            Ah[n] = *(const short8*)&WhP[off];
            Al[n] = *(const short8*)&WlP[off];
        }
        #pragma unroll
        for (int m = 0; m < 2; ++m) {
            size_t off = ((size_t)(b0 + wv * 32 + m * 16 + r) * NFIELDS + lp) * EMB
                       + kk * 32 + g * 8;
            Bh[m] = *(const short8*)&Fh[off];
            Bl[m] = *(const short8*)&Fl[off];
        }
        #pragma unroll
        for (int m = 0; m < 2; ++m)
            #pragma unroll
            for (int n = 0; n < 4; ++n) {
                // w*x ~= wl*xh + wh*xl + wh*xh   (drop wl*xl, err ~2^-16)
                acc[m][n] = __builtin_amdgcn_mfma_f32_16x16x32_bf16(Al[n], Bh[m], acc[m][n], 0, 0, 0);
                acc[m][n] = __builtin_amdgcn_mfma_f32_16x16x32_bf16(Ah[n], Bl[m], acc[m][n], 0, 0, 0);
                acc[m][n] = __builtin_amdgcn_mfma_f32_16x16x32_bf16(Ah[n], Bh[m], acc[m][n], 0, 0, 0);
            }
    }

    // epilogue: gate by R (fp32, exact) and store, fully 16B-vectorized
    #pragma unroll
    for (int m = 0; m < 2; ++m) {
        int b = b0 + wv * 32 + m * 16 + r;
        const float* Rr = femb + ((size_t)b * NFIELDS + rp) * EMB;
        float*       Or = out  + ((size_t)b * PAIRS   + p)  * EMB;
        #pragma unroll
        for (int n = 0; n < 4; ++n) {
            int e0 = n * 16 + g * 4;
            fvec4 rv = *(const fvec4*)&Rr[e0];
            fvec4 o  = acc[m][n] * rv;
            *(fvec4*)&Or[e0] = o;
        }
    }
}

extern "C" void kernel_launch(void* const* d_in, const int* in_sizes, int n_in,
                              void* d_out, int out_size, void* d_ws, size_t ws_size,
                              hipStream_t stream) {
    const float* femb = (const float*)d_in[0];
    const float* W    = (const float*)d_in[1];
    const int*   lidx = (const int*)d_in[2];
    const int*   ridx = (const int*)d_in[3];
    float*       out  = (float*)d_out;

    // workspace layout (33.8 MB total; ws is ~1.6 GB per the poison fills)
    unsigned short* Fh  = (unsigned short*)d_ws;
    unsigned short* Fl  = Fh + FEMB_ELEMS;
    unsigned short* Whg = Fl + FEMB_ELEMS;
    unsigned short* Wlg = Whg + W_ELEMS;

    prep_femb<<<FEMB_ELEMS / (256 * 8), 256, 0, stream>>>(femb, Fh, Fl);
    prep_w   <<<PAIRS, 256, 0, stream>>>(W, Whg, Wlg);
    bilinear_main<<<NBLOCKS, 256, 0, stream>>>(Fh, Fl, Whg, Wlg, femb, lidx, ridx, out);
}

// Round 8
// 527.186 us; speedup vs baseline: 1.1211x; 1.1211x over previous
//
#include <hip/hip_runtime.h>

#define BATCH   2048
#define NFIELDS 40
#define EMB     64
#define PAIRS   780
#define BM      128
#define NTILES  (BATCH / BM)          // 16
#define NBLOCKS (PAIRS * NTILES)      // 12480
#define FEMB_ELEMS (BATCH * NFIELDS * EMB)   // 5,242,880
#define W_ELEMS    (PAIRS * EMB * EMB)       // 3,194,880

typedef __attribute__((ext_vector_type(8))) short          short8;
typedef __attribute__((ext_vector_type(8))) unsigned short ushort8;
typedef __attribute__((ext_vector_type(4))) float          fvec4;

__device__ __forceinline__ unsigned short f2bf(float f) {
    unsigned int x = __float_as_uint(f);
    return (unsigned short)((x + 0x7fffu + ((x >> 16) & 1u)) >> 16);  // RTNE
}
__device__ __forceinline__ float bf2f(unsigned short h) {
    return __uint_as_float(((unsigned int)h) << 16);
}
struct bfpair { unsigned short h, l; };
__device__ __forceinline__ bfpair split1(float f) {
    bfpair r;
    r.h = f2bf(f);
    r.l = f2bf(f - bf2f(r.h));
    return r;
}

// Fragment layouts (chunk index == MFMA lane id l = g*16+r, so every
// fragment load in the main kernel is base + l*16B: one contiguous 1KB
// wave transaction):
//   Ffrag[b4][f][kk][l][8i] : element femb[b4*16 + (l&15)][f][kk*32+(l>>4)*8+i]
//   Wfrag[p][kk][n][l][8i]  : element W[p][kk*32+(l>>4)*8+i][n*16+(l&15)]
// (A-fragment lane l holds A[row=l&15][k=(l>>4)*8+i]; B-fragment lane l
//  holds B[k=(l>>4)*8+i][col=l&15] — m89/m91-verified mapping.)

// ---- prep 1: femb fp32 -> fragment-ordered hi/lo bf16 ----
// thread = (b4, f, r): reads one 256B row (full lines per lane), writes
// 16B chunks that are r-consecutive -> 256B contiguous per 16-lane group.
__global__ __launch_bounds__(256) void prep_femb(
    const float* __restrict__ femb, unsigned short* __restrict__ Fh,
    unsigned short* __restrict__ Fl)
{
    int tid = blockIdx.x * 256 + threadIdx.x;   // (b4*40 + f)*16 + r
    int r   = tid & 15;
    int bf  = tid >> 4;
    int f   = bf % NFIELDS;
    int b4  = bf / NFIELDS;

    const float* src = femb + ((size_t)(b4 * 16 + r) * NFIELDS + f) * EMB;
    ushort8 h8[8], l8[8];
    #pragma unroll
    for (int c = 0; c < 8; ++c) {               // 8 chunks of 8 elements
        fvec4 a = *(const fvec4*)&src[c * 8];
        fvec4 b = *(const fvec4*)&src[c * 8 + 4];
        #pragma unroll
        for (int i = 0; i < 4; ++i) {
            bfpair s0 = split1(a[i]); h8[c][i]     = s0.h; l8[c][i]     = s0.l;
            bfpair s1 = split1(b[i]); h8[c][i + 4] = s1.h; l8[c][i + 4] = s1.l;
        }
    }
    #pragma unroll
    for (int kk = 0; kk < 2; ++kk)
        #pragma unroll
        for (int g = 0; g < 4; ++g) {
            int c = kk * 4 + g;
            size_t dst = ((((size_t)bf * 2) + kk) * 64 + g * 16 + r) * 8;
            *(ushort8*)&Fh[dst] = h8[c];
            *(ushort8*)&Fl[dst] = l8[c];
        }
}

// ---- prep 2: W fp32 [p][k][e] -> fragment-ordered hi/lo bf16 (via LDS) ----
__global__ __launch_bounds__(256) void prep_w(
    const float* __restrict__ W, unsigned short* __restrict__ Wh,
    unsigned short* __restrict__ Wl)
{
    __shared__ float Ws[EMB * EMB];             // [k][e], 16KB
    int p = blockIdx.x;
    int t = threadIdx.x;
    const float* Wp = W + (size_t)p * (EMB * EMB);
    #pragma unroll
    for (int j = 0; j < 4; ++j)                 // coalesced 16KB copy
        *(fvec4*)&Ws[t * 16 + j * 4] = *(const fvec4*)&Wp[t * 16 + j * 4];
    __syncthreads();

    #pragma unroll
    for (int half = 0; half < 2; ++half) {
        int c  = t + half * 256;                // chunk id = (kk*4+n)*64 + l
        int kk = c >> 8;
        int n  = (c >> 6) & 3;
        int l  = c & 63;
        int r  = l & 15;
        int g  = l >> 4;
        ushort8 hi, lo;
        #pragma unroll
        for (int i = 0; i < 8; ++i) {           // 4-way LDS conflict: ok in prep
            bfpair s = split1(Ws[(kk * 32 + g * 8 + i) * EMB + n * 16 + r]);
            hi[i] = s.h; lo[i] = s.l;
        }
        size_t dst = (size_t)p * 4096 + (size_t)c * 8;   // coalesced write
        *(ushort8*)&Wh[dst] = hi;
        *(ushort8*)&Wl[dst] = lo;
    }
}

// ---- main: LDS-free, barrier-free, fully-coalesced fragment GEMM ----
// out[b][p][e] = (sum_k femb[b][lp][k] * W[p][k][e]) * femb[b][rp][e]
// A = L (rows=b), B = Wt (cols=e); D: col = l&15 -> e, row = (l>>4)*4+reg -> b
// => stores are 4 x 64B full-line segments per instruction.
__global__ __launch_bounds__(256, 4) void bilinear_main(
    const unsigned short* __restrict__ Fh, const unsigned short* __restrict__ Fl,
    const unsigned short* __restrict__ Wh, const unsigned short* __restrict__ Wl,
    const float* __restrict__ femb,
    const int* __restrict__ lidx, const int* __restrict__ ridx,
    float* __restrict__ out)
{
    // Bijective XCD swizzle (12480 % 8 == 0): each XCD owns a contiguous
    // p-range -> its Wfrag slice (~1.6MB) stays L2-resident.
    int d  = blockIdx.x;
    int w  = (d & 7) * (NBLOCKS / 8) + (d >> 3);
    int p  = w >> 4;
    int bt = w & 15;

    int lp = lidx[p];
    int rp = ridx[p];
    int t  = threadIdx.x;
    int wv = t >> 6;
    int l  = t & 63;
    int r  = l & 15;
    int g  = l >> 4;

    fvec4 acc[2][4] = {};
    #pragma unroll
    for (int kk = 0; kk < 2; ++kk) {
        short8 Bh[4], Bl[4];
        #pragma unroll
        for (int n = 0; n < 4; ++n) {           // 1KB contiguous per wave
            size_t off = ((size_t)p * 8 + kk * 4 + n) * 512 + l * 8;
            Bh[n] = *(const short8*)&Wh[off];
            Bl[n] = *(const short8*)&Wl[off];
        }
        short8 Ah[2], Al[2];
        #pragma unroll
        for (int m = 0; m < 2; ++m) {           // 1KB contiguous per wave
            int b4a = bt * 8 + wv * 2 + m;
            size_t off = (((size_t)b4a * NFIELDS + lp) * 2 + kk) * 512 + l * 8;
            Ah[m] = *(const short8*)&Fh[off];
            Al[m] = *(const short8*)&Fl[off];
        }
        #pragma unroll
        for (int m = 0; m < 2; ++m)
            #pragma unroll
            for (int n = 0; n < 4; ++n) {
                // a*w ~= al*wh + ah*wl + ah*wh  (drop al*wl, err ~2^-16)
                acc[m][n] = __builtin_amdgcn_mfma_f32_16x16x32_bf16(Al[m], Bh[n], acc[m][n], 0, 0, 0);
                acc[m][n] = __builtin_amdgcn_mfma_f32_16x16x32_bf16(Ah[m], Bl[n], acc[m][n], 0, 0, 0);
                acc[m][n] = __builtin_amdgcn_mfma_f32_16x16x32_bf16(Ah[m], Bh[n], acc[m][n], 0, 0, 0);
            }
    }

    // epilogue: gate by R (fp32, exact) and store; 4 x 64B segments / inst
    int b0 = bt * BM;
    #pragma unroll
    for (int m = 0; m < 2; ++m) {
        int bb = b0 + wv * 32 + m * 16 + g * 4;
        #pragma unroll
        for (int n = 0; n < 4; ++n) {
            int e = n * 16 + r;
            #pragma unroll
            for (int reg = 0; reg < 4; ++reg) {
                int b = bb + reg;
                float R = femb[((size_t)b * NFIELDS + rp) * EMB + e];
                out[((size_t)b * PAIRS + p) * EMB + e] = acc[m][n][reg] * R;
            }
        }
    }
}

extern "C" void kernel_launch(void* const* d_in, const int* in_sizes, int n_in,
                              void* d_out, int out_size, void* d_ws, size_t ws_size,
                              hipStream_t stream) {
    const float* femb = (const float*)d_in[0];
    const float* W    = (const float*)d_in[1];
    const int*   lidx = (const int*)d_in[2];
    const int*   ridx = (const int*)d_in[3];
    float*       out  = (float*)d_out;

    // workspace layout (33.8 MB total; ws is ~1.6 GB per the poison fills)
    unsigned short* Fh  = (unsigned short*)d_ws;
    unsigned short* Fl  = Fh + FEMB_ELEMS;
    unsigned short* Whg = Fl + FEMB_ELEMS;
    unsigned short* Wlg = Whg + W_ELEMS;

    prep_femb<<<(BATCH / 16) * NFIELDS * 16 / 256, 256, 0, stream>>>(femb, Fh, Fl);
    prep_w   <<<PAIRS, 256, 0, stream>>>(W, Whg, Wlg);
    bilinear_main<<<NBLOCKS, 256, 0, stream>>>(Fh, Fl, Whg, Wlg, femb, lidx, ridx, out);
}